// Round 1
// baseline (317.019 us; speedup 1.0000x reference)
//
#include <hip/hip_runtime.h>
#include <hip/hip_bf16.h>
#include <stdint.h>

#define D_MODEL 768
#define NH 12
#define DH 64
#define BB 2
#define TT 2048
#define BT (BB*TT)   // 4096 tokens

typedef unsigned short u16;
typedef __attribute__((ext_vector_type(8))) short short8;
typedef __attribute__((ext_vector_type(4))) float f32x4;

__device__ __forceinline__ u16 f2bf(float f) {
  union { float f; unsigned int u; } c; c.f = f;
  unsigned int u = c.u;
  u += 0x7fff + ((u >> 16) & 1);   // RNE
  return (u16)(u >> 16);
}

__device__ __forceinline__ void gload_lds16(const void* g, void* l) {
  __builtin_amdgcn_global_load_lds(
      (const __attribute__((address_space(1))) void*)g,
      (__attribute__((address_space(3))) void*)l, 16, 0, 0);
}

// ---------------- x -> bf16 (vectorized) ----------------
__global__ void k_convert_x(const float* __restrict__ in, u16* __restrict__ out, int n4) {
  int i = blockIdx.x * blockDim.x + threadIdx.x;
  if (i >= n4) return;
  float4 v = ((const float4*)in)[i];
  unsigned int p0 = (unsigned int)f2bf(v.x) | ((unsigned int)f2bf(v.y) << 16);
  unsigned int p1 = (unsigned int)f2bf(v.z) | ((unsigned int)f2bf(v.w) << 16);
  ((uint2*)out)[i] = make_uint2(p0, p1);
}

// ---------------- W [R][C] f32 -> W^T [C][R] bf16 ----------------
__global__ void k_transpose_bf16(const float* __restrict__ in, u16* __restrict__ out, int R, int C) {
  __shared__ float tile[32][33];
  int bc = blockIdx.x * 32;   // col base
  int br = blockIdx.y * 32;   // row base
  int tx = threadIdx.x, ty = threadIdx.y;   // 32 x 8
  #pragma unroll
  for (int i = 0; i < 32; i += 8)
    tile[ty + i][tx] = in[(size_t)(br + ty + i) * C + bc + tx];
  __syncthreads();
  #pragma unroll
  for (int i = 0; i < 32; i += 8)
    out[(size_t)(bc + ty + i) * R + br + tx] = f2bf(tile[tx][ty + i]);
}

// ---------------- GEMM: [M][K]bf16 x [N][K]bf16^T, 128x128 tile, 4 waves ----------------
// MODE 0: QKV projection, epilogue scatters Q,K -> [B,H,T,64], V -> [B,H,64,T] (+bias)
// MODE 1: out = z @ Wo + bo, f32 output
template<int MODE>
__global__ __launch_bounds__(256, 2)
void k_gemm(const u16* __restrict__ Abf, const u16* __restrict__ Bt,
            const float* __restrict__ bias0, const float* __restrict__ bias1,
            const float* __restrict__ bias2,
            u16* __restrict__ q_buf, u16* __restrict__ k_buf, u16* __restrict__ vt_buf,
            float* __restrict__ out, int K) {
  __shared__ u16 As[128 * 32];
  __shared__ u16 Bs[128 * 32];
  int tid = threadIdx.x;
  int lane = tid & 63, w = tid >> 6;
  int ln = lane & 15, lg = lane >> 4;
  int wm = w >> 1, wn = w & 1;
  int m0 = blockIdx.y * 128, n0 = blockIdx.x * 128;
  f32x4 acc[4][4] = {};
  int c0 = tid, c1 = tid + 256;

  for (int kb = 0; kb < K; kb += 32) {
    gload_lds16(Abf + (size_t)(m0 + (c0 >> 2)) * K + kb + (c0 & 3) * 8, (char*)As + c0 * 16);
    gload_lds16(Abf + (size_t)(m0 + (c1 >> 2)) * K + kb + (c1 & 3) * 8, (char*)As + c1 * 16);
    gload_lds16(Bt  + (size_t)(n0 + (c0 >> 2)) * K + kb + (c0 & 3) * 8, (char*)Bs + c0 * 16);
    gload_lds16(Bt  + (size_t)(n0 + (c1 >> 2)) * K + kb + (c1 & 3) * 8, (char*)Bs + c1 * 16);
    __syncthreads();
    short8 af[4], bfr[4];
    #pragma unroll
    for (int mt = 0; mt < 4; ++mt)
      af[mt] = *(const short8*)&As[(wm * 64 + mt * 16 + ln) * 32 + lg * 8];
    #pragma unroll
    for (int nt = 0; nt < 4; ++nt)
      bfr[nt] = *(const short8*)&Bs[(wn * 64 + nt * 16 + ln) * 32 + lg * 8];
    #pragma unroll
    for (int mt = 0; mt < 4; ++mt)
      #pragma unroll
      for (int nt = 0; nt < 4; ++nt)
        acc[mt][nt] = __builtin_amdgcn_mfma_f32_16x16x32_bf16(af[mt], bfr[nt], acc[mt][nt], 0, 0, 0);
    __syncthreads();
  }

  #pragma unroll
  for (int mt = 0; mt < 4; ++mt) {
    #pragma unroll
    for (int nt = 0; nt < 4; ++nt) {
      #pragma unroll
      for (int r = 0; r < 4; ++r) {
        int row = m0 + wm * 64 + mt * 16 + lg * 4 + r;   // token index
        int col = n0 + wn * 64 + nt * 16 + ln;
        float v = acc[mt][nt][r];
        if (MODE == 0) {
          int b = row >> 11, t = row & 2047;
          if (col < 768) {
            v += bias0[col];
            int h = col >> 6, d = col & 63;
            q_buf[(((size_t)b * NH + h) * TT + t) * DH + d] = f2bf(v);
          } else if (col < 1536) {
            int c2 = col - 768; v += bias1[c2];
            int h = c2 >> 6, d = c2 & 63;
            k_buf[(((size_t)b * NH + h) * TT + t) * DH + d] = f2bf(v);
          } else {
            int c2 = col - 1536; v += bias2[c2];
            int h = c2 >> 6, d = c2 & 63;
            vt_buf[(((size_t)b * NH + h) * DH + d) * TT + t] = f2bf(v);   // V transposed
          }
        } else {
          out[(size_t)row * 768 + col] = v + bias0[col];
        }
      }
    }
  }
}

// ---------------- Attention: one WG = 16 q-rows of one (b,h); 4 waves x 512 keys ----------------
__global__ __launch_bounds__(256, 2)
void k_attn(const u16* __restrict__ Q, const u16* __restrict__ Kb,
            const u16* __restrict__ Vt, const float* __restrict__ gates,
            float* __restrict__ A_out, u16* __restrict__ z_buf) {
  int bh = blockIdx.y;
  int b = bh / NH, h = bh % NH;
  int q0 = blockIdx.x * 16;
  int tid = threadIdx.x;
  int lane = tid & 63, w = tid >> 6;
  int ln = lane & 15, lg = lane >> 4;
  const u16* Qbh = Q  + (size_t)bh * TT * DH;
  const u16* Kbh = Kb + (size_t)bh * TT * DH;
  const u16* Vbh = Vt + (size_t)bh * DH * TT;
  float gate = gates[bh];

  // Q fragments (A-operand: m=q-row on ln, k on lg*8+j), hoisted
  short8 qf0 = *(const short8*)&Qbh[(size_t)(q0 + ln) * DH + lg * 8];
  short8 qf1 = *(const short8*)&Qbh[(size_t)(q0 + ln) * DH + 32 + lg * 8];

  int key_base = w * 512;
  f32x4 sacc[32];
  #pragma unroll
  for (int t = 0; t < 32; ++t) {
    const u16* kp = &Kbh[(size_t)(key_base + t * 16 + ln) * DH + lg * 8];
    short8 kf0 = *(const short8*)kp;
    short8 kf1 = *(const short8*)(kp + 32);
    f32x4 c = {0.f, 0.f, 0.f, 0.f};
    c = __builtin_amdgcn_mfma_f32_16x16x32_bf16(qf0, kf0, c, 0, 0, 0);
    c = __builtin_amdgcn_mfma_f32_16x16x32_bf16(qf1, kf1, c, 0, 0, 0);
    sacc[t] = c;   // D: key = ln + 16t, q = lg*4 + r
  }

  __shared__ float red_m[4][16];
  __shared__ float red_s[4][16];

  // per-row max: in-lane over 32 tiles, then butterfly over the 16-lane group
  float mr[4];
  #pragma unroll
  for (int r = 0; r < 4; ++r) {
    float m = sacc[0][r];
    #pragma unroll
    for (int t = 1; t < 32; ++t) m = fmaxf(m, sacc[t][r]);
    #pragma unroll
    for (int mk = 1; mk <= 8; mk <<= 1) m = fmaxf(m, __shfl_xor(m, mk, 64));
    mr[r] = m;
  }
  if (ln == 0) {
    #pragma unroll
    for (int r = 0; r < 4; ++r) red_m[w][lg * 4 + r] = mr[r];
  }
  __syncthreads();
  float gm[4];
  #pragma unroll
  for (int r = 0; r < 4; ++r) {
    int q = lg * 4 + r;
    gm[r] = fmaxf(fmaxf(red_m[0][q], red_m[1][q]), fmaxf(red_m[2][q], red_m[3][q]));
  }

  const float cs = 0.18033688011112042f;   // log2(e)/8  (1/sqrt(64) folded)
  float sr[4] = {0.f, 0.f, 0.f, 0.f};
  #pragma unroll
  for (int t = 0; t < 32; ++t) {
    #pragma unroll
    for (int r = 0; r < 4; ++r) {
      float e = exp2f((sacc[t][r] - gm[r]) * cs);
      sacc[t][r] = e;
      sr[r] += e;
    }
  }
  #pragma unroll
  for (int r = 0; r < 4; ++r) {
    #pragma unroll
    for (int mk = 1; mk <= 8; mk <<= 1) sr[r] += __shfl_xor(sr[r], mk, 64);
  }
  if (ln == 0) {
    #pragma unroll
    for (int r = 0; r < 4; ++r) red_s[w][lg * 4 + r] = sr[r];
  }
  __syncthreads();
  float scale[4];
  #pragma unroll
  for (int r = 0; r < 4; ++r) {
    int q = lg * 4 + r;
    float denom = red_s[0][q] + red_s[1][q] + red_s[2][q] + red_s[3][q];
    scale[r] = gate / denom;   // gate folded post-softmax
  }

  // Gated A write (f32, exactly once) + chunked P->LDS (wave-private) -> PV MFMA
  float* Arow = A_out + ((size_t)bh * TT + q0) * TT;
  __shared__ u16 P_lds[4][16][136];
  f32x4 zacc[4] = {};
  #pragma unroll
  for (int ch = 0; ch < 4; ++ch) {
    #pragma unroll
    for (int tt = 0; tt < 8; ++tt) {
      int t = ch * 8 + tt;
      int key = key_base + t * 16 + ln;
      #pragma unroll
      for (int r = 0; r < 4; ++r) {
        float p = sacc[t][r] * scale[r];
        Arow[(size_t)(lg * 4 + r) * TT + key] = p;
        P_lds[w][lg * 4 + r][tt * 16 + ln] = f2bf(p);
      }
    }
    // PV over this 128-key chunk: A-operand from LDS (q=ln, k=lg*8+j), B from V^T (d=ln)
    #pragma unroll
    for (int ks = 0; ks < 4; ++ks) {
      short8 pf = *(const short8*)&P_lds[w][ln][ks * 32 + lg * 8];
      #pragma unroll
      for (int dt = 0; dt < 4; ++dt) {
        const u16* vp = &Vbh[(size_t)(dt * 16 + ln) * TT + key_base + ch * 128 + ks * 32 + lg * 8];
        short8 vf = *(const short8*)vp;
        zacc[dt] = __builtin_amdgcn_mfma_f32_16x16x32_bf16(pf, vf, zacc[dt], 0, 0, 0);
      }
    }
  }

  // cross-wave Z reduce
  __shared__ float Zred[4][16][64];
  #pragma unroll
  for (int dt = 0; dt < 4; ++dt)
    #pragma unroll
    for (int r = 0; r < 4; ++r)
      Zred[w][lg * 4 + r][dt * 16 + ln] = zacc[dt][r];
  __syncthreads();
  {
    int d = lane;
    #pragma unroll
    for (int i = 0; i < 4; ++i) {
      int qq = w + i * 4;
      float s = Zred[0][qq][d] + Zred[1][qq][d] + Zred[2][qq][d] + Zred[3][qq][d];
      z_buf[((size_t)b * TT + q0 + qq) * D_MODEL + h * DH + d] = f2bf(s);
    }
  }
}

extern "C" void kernel_launch(void* const* d_in, const int* in_sizes, int n_in,
                              void* d_out, int out_size, void* d_ws, size_t ws_size,
                              hipStream_t stream) {
  const float* x     = (const float*)d_in[0];
  const float* gates = (const float*)d_in[1];
  const float* Wq    = (const float*)d_in[2];
  const float* bq    = (const float*)d_in[3];
  const float* Wk    = (const float*)d_in[4];
  const float* bk    = (const float*)d_in[5];
  const float* Wv    = (const float*)d_in[6];
  const float* bv    = (const float*)d_in[7];
  const float* Wo    = (const float*)d_in[8];
  const float* bo    = (const float*)d_in[9];
  float* out   = (float*)d_out;
  float* A_out = out + (size_t)BT * D_MODEL;

  char* ws = (char*)d_ws;
  u16* x_bf   = (u16*)ws; ws += (size_t)BT * D_MODEL * 2;
  u16* wqkvT  = (u16*)ws; ws += (size_t)3 * D_MODEL * D_MODEL * 2;
  u16* woT    = (u16*)ws; ws += (size_t)D_MODEL * D_MODEL * 2;
  u16* q_buf  = (u16*)ws; ws += (size_t)BT * D_MODEL * 2;
  u16* k_buf  = (u16*)ws; ws += (size_t)BT * D_MODEL * 2;
  u16* vt_buf = (u16*)ws; ws += (size_t)BT * D_MODEL * 2;
  u16* z_buf  = (u16*)ws; ws += (size_t)BT * D_MODEL * 2;

  k_convert_x<<<(BT * D_MODEL / 4 + 255) / 256, 256, 0, stream>>>(x, x_bf, BT * D_MODEL / 4);
  dim3 tb(32, 8);
  dim3 tg(D_MODEL / 32, D_MODEL / 32);
  k_transpose_bf16<<<tg, tb, 0, stream>>>(Wq, wqkvT, D_MODEL, D_MODEL);
  k_transpose_bf16<<<tg, tb, 0, stream>>>(Wk, wqkvT + (size_t)D_MODEL * D_MODEL, D_MODEL, D_MODEL);
  k_transpose_bf16<<<tg, tb, 0, stream>>>(Wv, wqkvT + (size_t)2 * D_MODEL * D_MODEL, D_MODEL, D_MODEL);
  k_transpose_bf16<<<tg, tb, 0, stream>>>(Wo, woT, D_MODEL, D_MODEL);

  k_gemm<0><<<dim3(2304 / 128, BT / 128), 256, 0, stream>>>(
      x_bf, wqkvT, bq, bk, bv, q_buf, k_buf, vt_buf, nullptr, D_MODEL);

  k_attn<<<dim3(TT / 16, BB * NH), 256, 0, stream>>>(q_buf, k_buf, vt_buf, gates, A_out, z_buf);

  k_gemm<1><<<dim3(D_MODEL / 128, BT / 128), 256, 0, stream>>>(
      z_buf, woT, bo, nullptr, nullptr, nullptr, nullptr, nullptr, out, D_MODEL);
}

// Round 3
// 283.801 us; speedup vs baseline: 1.1170x; 1.1170x over previous
//
#include <hip/hip_runtime.h>
#include <hip/hip_bf16.h>
#include <stdint.h>

#define D_MODEL 768
#define NH 12
#define DH 64
#define BB 2
#define TT 2048
#define BT (BB*TT)   // 4096 tokens
#define NW 8         // waves per attn block
#define KPW 256      // keys per wave

typedef unsigned short u16;
typedef __attribute__((ext_vector_type(8))) short short8;
typedef __attribute__((ext_vector_type(4))) float f32x4;
typedef __attribute__((ext_vector_type(2))) float f32x2;
typedef __attribute__((ext_vector_type(2))) __fp16 half2v;

__device__ __forceinline__ u16 f2bf(float f) {
  union { float f; unsigned int u; } c; c.f = f;
  unsigned int u = c.u;
  u += 0x7fff + ((u >> 16) & 1);   // RNE
  return (u16)(u >> 16);
}

__device__ __forceinline__ float bf2f(u16 b) {
  union { unsigned int u; float f; } c; c.u = ((unsigned int)b) << 16;
  return c.f;
}

__device__ __forceinline__ void gload_lds16(const void* g, void* l) {
  __builtin_amdgcn_global_load_lds(
      (const __attribute__((address_space(1))) void*)g,
      (__attribute__((address_space(3))) void*)l, 16, 0, 0);
}

// ---------------- x -> bf16 (vectorized) ----------------
__global__ void k_convert_x(const float* __restrict__ in, u16* __restrict__ out, int n4) {
  int i = blockIdx.x * blockDim.x + threadIdx.x;
  if (i >= n4) return;
  float4 v = ((const float4*)in)[i];
  unsigned int p0 = (unsigned int)f2bf(v.x) | ((unsigned int)f2bf(v.y) << 16);
  unsigned int p1 = (unsigned int)f2bf(v.z) | ((unsigned int)f2bf(v.w) << 16);
  ((uint2*)out)[i] = make_uint2(p0, p1);
}

// ---------------- W [R][C] f32 -> W^T [C][R] bf16 ----------------
__global__ void k_transpose_bf16(const float* __restrict__ in, u16* __restrict__ out, int R, int C) {
  __shared__ float tile[32][33];
  int bc = blockIdx.x * 32;   // col base
  int br = blockIdx.y * 32;   // row base
  int tx = threadIdx.x, ty = threadIdx.y;   // 32 x 8
  #pragma unroll
  for (int i = 0; i < 32; i += 8)
    tile[ty + i][tx] = in[(size_t)(br + ty + i) * C + bc + tx];
  __syncthreads();
  #pragma unroll
  for (int i = 0; i < 32; i += 8)
    out[(size_t)(bc + ty + i) * R + br + tx] = f2bf(tile[tx][ty + i]);
}

// ---------------- GEMM: [M][K]bf16 x [N][K]bf16^T, 128x128 tile, 4 waves ----------------
template<int MODE>
__global__ __launch_bounds__(256, 2)
void k_gemm(const u16* __restrict__ Abf, const u16* __restrict__ Bt,
            const float* __restrict__ bias0, const float* __restrict__ bias1,
            const float* __restrict__ bias2,
            u16* __restrict__ q_buf, u16* __restrict__ k_buf, u16* __restrict__ vt_buf,
            float* __restrict__ out, int K) {
  __shared__ u16 As[128 * 32];
  __shared__ u16 Bs[128 * 32];
  int tid = threadIdx.x;
  int lane = tid & 63, w = tid >> 6;
  int ln = lane & 15, lg = lane >> 4;
  int wm = w >> 1, wn = w & 1;
  int m0 = blockIdx.y * 128, n0 = blockIdx.x * 128;
  f32x4 acc[4][4] = {};
  int c0 = tid, c1 = tid + 256;

  for (int kb = 0; kb < K; kb += 32) {
    gload_lds16(Abf + (size_t)(m0 + (c0 >> 2)) * K + kb + (c0 & 3) * 8, (char*)As + c0 * 16);
    gload_lds16(Abf + (size_t)(m0 + (c1 >> 2)) * K + kb + (c1 & 3) * 8, (char*)As + c1 * 16);
    gload_lds16(Bt  + (size_t)(n0 + (c0 >> 2)) * K + kb + (c0 & 3) * 8, (char*)Bs + c0 * 16);
    gload_lds16(Bt  + (size_t)(n0 + (c1 >> 2)) * K + kb + (c1 & 3) * 8, (char*)Bs + c1 * 16);
    __syncthreads();
    short8 af[4], bfr[4];
    #pragma unroll
    for (int mt = 0; mt < 4; ++mt)
      af[mt] = *(const short8*)&As[(wm * 64 + mt * 16 + ln) * 32 + lg * 8];
    #pragma unroll
    for (int nt = 0; nt < 4; ++nt)
      bfr[nt] = *(const short8*)&Bs[(wn * 64 + nt * 16 + ln) * 32 + lg * 8];
    #pragma unroll
    for (int mt = 0; mt < 4; ++mt)
      #pragma unroll
      for (int nt = 0; nt < 4; ++nt)
        acc[mt][nt] = __builtin_amdgcn_mfma_f32_16x16x32_bf16(af[mt], bfr[nt], acc[mt][nt], 0, 0, 0);
    __syncthreads();
  }

  #pragma unroll
  for (int mt = 0; mt < 4; ++mt) {
    #pragma unroll
    for (int nt = 0; nt < 4; ++nt) {
      #pragma unroll
      for (int r = 0; r < 4; ++r) {
        int row = m0 + wm * 64 + mt * 16 + lg * 4 + r;   // token index
        int col = n0 + wn * 64 + nt * 16 + ln;
        float v = acc[mt][nt][r];
        if (MODE == 0) {
          int b = row >> 11, t = row & 2047;
          if (col < 768) {
            v += bias0[col];
            int h = col >> 6, d = col & 63;
            q_buf[(((size_t)b * NH + h) * TT + t) * DH + d] = f2bf(v);
          } else if (col < 1536) {
            int c2 = col - 768; v += bias1[c2];
            int h = c2 >> 6, d = c2 & 63;
            k_buf[(((size_t)b * NH + h) * TT + t) * DH + d] = f2bf(v);
          } else {
            int c2 = col - 1536; v += bias2[c2];
            int h = c2 >> 6, d = c2 & 63;
            vt_buf[(((size_t)b * NH + h) * DH + d) * TT + t] = f2bf(v);   // V transposed
          }
        } else {
          out[(size_t)row * 768 + col] = v + bias0[col];
        }
      }
    }
  }
}

// ---------------- Attention: one WG = 16 q-rows of one (b,h); 8 waves x 256 keys ----------------
union AttnSM {
  u16  P[NW][16][136];   // bf16 gated P, per-wave chunk staging (34.8 KB)
  float Z[NW][16][72];   // cross-wave z reduce (36.9 KB), pad 72 -> 2-way banks
};

__global__ __launch_bounds__(512, 4)
void k_attn(const u16* __restrict__ Q, const u16* __restrict__ Kb,
            const u16* __restrict__ Vt, const float* __restrict__ gates,
            float* __restrict__ A_out, u16* __restrict__ z_buf) {
  int bh = blockIdx.y;
  int b = bh / NH, h = bh % NH;
  int q0 = blockIdx.x * 16;
  int tid = threadIdx.x;
  int lane = tid & 63, w = tid >> 6;
  int ln = lane & 15, lg = lane >> 4;
  const u16* Qbh = Q  + (size_t)bh * TT * DH;
  const u16* Kbh = Kb + (size_t)bh * TT * DH;
  const u16* Vbh = Vt + (size_t)bh * DH * TT;
  float gate = gates[bh];

  __shared__ float red_m[NW][16];
  __shared__ float red_s[NW][16];
  __shared__ AttnSM sm;

  // Q fragments (A-operand: m=q-row on ln, k on lg*8+j)
  short8 qf0 = *(const short8*)&Qbh[(size_t)(q0 + ln) * DH + lg * 8];
  short8 qf1 = *(const short8*)&Qbh[(size_t)(q0 + ln) * DH + 32 + lg * 8];

  int base = w * KPW;

  // ---- pass 1: QK^T, stash S as packed f16 (32 VGPRs), track per-lane row max ----
  half2v sh[16][2];
  float m[4] = {-1e30f, -1e30f, -1e30f, -1e30f};
  #pragma unroll
  for (int t = 0; t < 16; ++t) {
    const u16* kp = &Kbh[(size_t)(base + t * 16 + ln) * DH + lg * 8];
    short8 kf0 = *(const short8*)kp;
    short8 kf1 = *(const short8*)(kp + 32);
    f32x4 c = {0.f, 0.f, 0.f, 0.f};
    c = __builtin_amdgcn_mfma_f32_16x16x32_bf16(qf0, kf0, c, 0, 0, 0);
    c = __builtin_amdgcn_mfma_f32_16x16x32_bf16(qf1, kf1, c, 0, 0, 0);
    sh[t][0] = __builtin_amdgcn_cvt_pkrtz(c[0], c[1]);
    sh[t][1] = __builtin_amdgcn_cvt_pkrtz(c[2], c[3]);
    m[0] = fmaxf(m[0], c[0]); m[1] = fmaxf(m[1], c[1]);
    m[2] = fmaxf(m[2], c[2]); m[3] = fmaxf(m[3], c[3]);
  }

  // cross-lane max over the 16-lane key group, then cross-wave via LDS
  #pragma unroll
  for (int r = 0; r < 4; ++r)
    #pragma unroll
    for (int mk = 1; mk <= 8; mk <<= 1) m[r] = fmaxf(m[r], __shfl_xor(m[r], mk, 64));
  if (ln == 0) {
    #pragma unroll
    for (int r = 0; r < 4; ++r) red_m[w][lg * 4 + r] = m[r];
  }
  __syncthreads();
  float gm[4];
  #pragma unroll
  for (int r = 0; r < 4; ++r) {
    int q = lg * 4 + r;
    float v = red_m[0][q];
    #pragma unroll
    for (int i = 1; i < NW; ++i) v = fmaxf(v, red_m[i][q]);
    gm[r] = v;
  }

  // ---- pass 2: e = exp2((s-gm)*cs), store back as f16, accumulate row sums ----
  const float cs = 0.18033688011112042f;   // log2(e)/sqrt(64)
  float sr[4] = {0.f, 0.f, 0.f, 0.f};
  #pragma unroll
  for (int t = 0; t < 16; ++t) {
    #pragma unroll
    for (int j = 0; j < 2; ++j) {
      float s0 = (float)sh[t][j][0], s1 = (float)sh[t][j][1];
      float e0 = exp2f((s0 - gm[j * 2]) * cs);
      float e1 = exp2f((s1 - gm[j * 2 + 1]) * cs);
      sh[t][j] = __builtin_amdgcn_cvt_pkrtz(e0, e1);
      sr[j * 2] += e0; sr[j * 2 + 1] += e1;
    }
  }
  #pragma unroll
  for (int r = 0; r < 4; ++r)
    #pragma unroll
    for (int mk = 1; mk <= 8; mk <<= 1) sr[r] += __shfl_xor(sr[r], mk, 64);
  if (ln == 0) {
    #pragma unroll
    for (int r = 0; r < 4; ++r) red_s[w][lg * 4 + r] = sr[r];
  }
  __syncthreads();
  float scale[4];
  #pragma unroll
  for (int r = 0; r < 4; ++r) {
    int q = lg * 4 + r;
    float denom = red_s[0][q];
    #pragma unroll
    for (int i = 1; i < NW; ++i) denom += red_s[i][q];
    scale[r] = gate / denom;   // gate folded post-softmax
  }

  // ---- pass 3: per 128-key chunk: P->LDS (bf16), PV MFMA, coalesced nt A-write ----
  float* Arow = A_out + ((size_t)bh * TT + q0) * TT;
  f32x4 zacc[4] = {};
  #pragma unroll
  for (int ch = 0; ch < 2; ++ch) {
    #pragma unroll
    for (int tt = 0; tt < 8; ++tt) {
      int t = ch * 8 + tt;
      #pragma unroll
      for (int r = 0; r < 4; ++r) {
        float p = (float)sh[t][r >> 1][r & 1] * scale[r];
        sm.P[w][lg * 4 + r][tt * 16 + ln] = f2bf(p);
      }
    }
    // PV over this 128-key chunk
    #pragma unroll
    for (int ks = 0; ks < 4; ++ks) {
      short8 pf = *(const short8*)&sm.P[w][ln][ks * 32 + lg * 8];
      #pragma unroll
      for (int dt = 0; dt < 4; ++dt) {
        const u16* vp = &Vbh[(size_t)(dt * 16 + ln) * TT + base + ch * 128 + ks * 32 + lg * 8];
        short8 vf = *(const short8*)vp;
        zacc[dt] = __builtin_amdgcn_mfma_f32_16x16x32_bf16(pf, vf, zacc[dt], 0, 0, 0);
      }
    }
    // coalesced A-write: 64 lanes x 8B = 512B contiguous per row, nontemporal
    #pragma unroll
    for (int row = 0; row < 16; ++row) {
      unsigned int pk = *(const unsigned int*)&sm.P[w][row][lane * 2];
      f32x2 v2;
      v2.x = bf2f((u16)pk);
      v2.y = bf2f((u16)(pk >> 16));
      __builtin_nontemporal_store(v2,
          (f32x2*)&Arow[(size_t)row * TT + base + ch * 128 + lane * 2]);
    }
  }

  // ---- cross-wave Z reduce (reuses P's LDS) ----
  __syncthreads();
  #pragma unroll
  for (int dt = 0; dt < 4; ++dt)
    #pragma unroll
    for (int r = 0; r < 4; ++r)
      sm.Z[w][lg * 4 + r][dt * 16 + ln] = zacc[dt][r];
  __syncthreads();
  {
    int d = lane;
    #pragma unroll
    for (int i = 0; i < 2; ++i) {
      int qq = w + i * 8;
      float s = 0.f;
      #pragma unroll
      for (int j = 0; j < NW; ++j) s += sm.Z[j][qq][d];
      z_buf[((size_t)b * TT + q0 + qq) * D_MODEL + h * DH + d] = f2bf(s);
    }
  }
}

extern "C" void kernel_launch(void* const* d_in, const int* in_sizes, int n_in,
                              void* d_out, int out_size, void* d_ws, size_t ws_size,
                              hipStream_t stream) {
  const float* x     = (const float*)d_in[0];
  const float* gates = (const float*)d_in[1];
  const float* Wq    = (const float*)d_in[2];
  const float* bq    = (const float*)d_in[3];
  const float* Wk    = (const float*)d_in[4];
  const float* bk    = (const float*)d_in[5];
  const float* Wv    = (const float*)d_in[6];
  const float* bv    = (const float*)d_in[7];
  const float* Wo    = (const float*)d_in[8];
  const float* bo    = (const float*)d_in[9];
  float* out   = (float*)d_out;
  float* A_out = out + (size_t)BT * D_MODEL;

  char* ws = (char*)d_ws;
  u16* x_bf   = (u16*)ws; ws += (size_t)BT * D_MODEL * 2;
  u16* wqkvT  = (u16*)ws; ws += (size_t)3 * D_MODEL * D_MODEL * 2;
  u16* woT    = (u16*)ws; ws += (size_t)D_MODEL * D_MODEL * 2;
  u16* q_buf  = (u16*)ws; ws += (size_t)BT * D_MODEL * 2;
  u16* k_buf  = (u16*)ws; ws += (size_t)BT * D_MODEL * 2;
  u16* vt_buf = (u16*)ws; ws += (size_t)BT * D_MODEL * 2;
  u16* z_buf  = (u16*)ws; ws += (size_t)BT * D_MODEL * 2;

  k_convert_x<<<(BT * D_MODEL / 4 + 255) / 256, 256, 0, stream>>>(x, x_bf, BT * D_MODEL / 4);
  dim3 tb(32, 8);
  dim3 tg(D_MODEL / 32, D_MODEL / 32);
  k_transpose_bf16<<<tg, tb, 0, stream>>>(Wq, wqkvT, D_MODEL, D_MODEL);
  k_transpose_bf16<<<tg, tb, 0, stream>>>(Wk, wqkvT + (size_t)D_MODEL * D_MODEL, D_MODEL, D_MODEL);
  k_transpose_bf16<<<tg, tb, 0, stream>>>(Wv, wqkvT + (size_t)2 * D_MODEL * D_MODEL, D_MODEL, D_MODEL);
  k_transpose_bf16<<<tg, tb, 0, stream>>>(Wo, woT, D_MODEL, D_MODEL);

  k_gemm<0><<<dim3(2304 / 128, BT / 128), 256, 0, stream>>>(
      x_bf, wqkvT, bq, bk, bv, q_buf, k_buf, vt_buf, nullptr, D_MODEL);

  k_attn<<<dim3(TT / 16, BB * NH), 512, 0, stream>>>(q_buf, k_buf, vt_buf, gates, A_out, z_buf);

  k_gemm<1><<<dim3(D_MODEL / 128, BT / 128), 256, 0, stream>>>(
      z_buf, woT, bo, nullptr, nullptr, nullptr, nullptr, nullptr, out, D_MODEL);
}